// Round 1
// baseline (296.840 us; speedup 1.0000x reference)
//
#include <hip/hip_runtime.h>

// Dims (fixed by the reference)
#define NN 1024
// K padded: 64 (ns) + 3 (coords) + 1 (bias) = 68 -> pad to 96 = 3 x 32
#define KP 96
#define LSTR 104   // LDS row stride in shorts (208 B; dword stride 52 -> 2-way banks, free)

typedef __attribute__((ext_vector_type(8))) short short8;
typedef __attribute__((ext_vector_type(4))) short short4v;
typedef __attribute__((ext_vector_type(4))) float f32x4;

__device__ __forceinline__ short f2bf(float f){
  unsigned u = __builtin_bit_cast(unsigned, f);
  u += 0x7FFFu + ((u >> 16) & 1u);       // RNE
  return (short)(u >> 16);
}

// ---------------- fused prep: PT panel (bf16) + B panel + V panel ----------
// blocks 0..95   : PTbf[h][kk][c] = bf16( sum_d Wq[h*1024+d][c] * X[d][kk] )
//                  h = r/12, kk octet = (r%12)*8; no atomics (full d-sum per block)
// blocks 96..159 : Bm[b][m][kk] bf16  (as before)
// blocks 160..287: Vm[o][kk]   bf16  (as before)
__global__ __launch_bounds__(256) void prep_all(
    const float* __restrict__ Wq, const float* __restrict__ Wk,
    const float* __restrict__ Wlq, const float* __restrict__ blq,
    const float* __restrict__ ns, const float* __restrict__ coord,
    const float* __restrict__ Wv, const float* __restrict__ Wlv,
    const float* __restrict__ blv,
    short* __restrict__ PTbf, short* __restrict__ Bm, short* __restrict__ Vm){
  __shared__ union SU {
    float red[4][64][9];                       // PT partial sums (pad 9: no conflicts)
    struct { float nsT[64][65]; float cst[3][64]; } bb;
  } S;
  const int t = threadIdx.x;
  const int r = blockIdx.x;

  if (r < 96){
    // ---- PT panel ----
    const int h = r / 12, kidx = r % 12, kk0 = kidx * 8;
    const int c = t & 63, p = t >> 6;            // p: 0..3 d-partitions of 256
    if (kidx > 8){                               // pure pad rows: write zeros
      if (p == 0){
        #pragma unroll
        for (int j = 0; j < 8; ++j) PTbf[(h*96 + kk0 + j)*64 + c] = 0;
      }
      return;
    }
    float acc[8];
    #pragma unroll
    for (int j = 0; j < 8; ++j) acc[j] = 0.f;
    if (kidx < 8){
      #pragma unroll 4
      for (int i = 0; i < 256; ++i){
        const int o = h*1024 + p*256 + i;
        const float wq = Wq[o*64 + c];           // coalesced over c
        const float* wk = Wk + o*64 + kk0;       // wave-uniform row
        f32x4 b0 = *(const f32x4*)(wk);
        f32x4 b1 = *(const f32x4*)(wk + 4);
        #pragma unroll
        for (int j = 0; j < 4; ++j){ acc[j] += wq*b0[j]; acc[4+j] += wq*b1[j]; }
      }
    } else {                                     // kidx==8: kk 64..71 (Wlq/blq/pad)
      #pragma unroll 4
      for (int i = 0; i < 256; ++i){
        const int o = h*1024 + p*256 + i;
        const float wq = Wq[o*64 + c];
        acc[0] += wq * Wlq[o*3 + 0];
        acc[1] += wq * Wlq[o*3 + 1];
        acc[2] += wq * Wlq[o*3 + 2];
        acc[3] += wq * blq[o];
      }
    }
    #pragma unroll
    for (int j = 0; j < 8; ++j) S.red[p][c][j] = acc[j];
    __syncthreads();
    if (p == 0){
      #pragma unroll
      for (int j = 0; j < 8; ++j){
        float s = S.red[0][c][j] + S.red[1][c][j] + S.red[2][c][j] + S.red[3][c][j];
        PTbf[(h*96 + kk0 + j)*64 + c] = f2bf(s);
      }
    }
  } else if (r < 160){
    // ---- B panel ----
    const int rb = r - 96;
    const int b = rb >> 4, m0 = (rb & 15) * 64;
    #pragma unroll
    for (int it = 0; it < 16; ++it){
      int idx = it * 256 + t;
      int c = idx >> 6, mm = idx & 63;
      S.bb.nsT[mm][c] = ns[(b*64 + c)*NN + m0 + mm];   // coalesced over mm
    }
    if (t < 192){
      int j = t >> 6, mm = t & 63;
      S.bb.cst[j][mm] = coord[(b*3 + j)*NN + m0 + mm];
    }
    __syncthreads();
    #pragma unroll
    for (int it = 0; it < 24; ++it){
      int idx = it * 256 + t;                          // 64*96 = 6144
      int mm = idx / KP, kk = idx - mm*KP;
      float v = (kk < 64) ? S.bb.nsT[mm][kk]
              : (kk < 67) ? S.bb.cst[kk - 64][mm]
              : (kk == 67) ? 1.f : 0.f;
      Bm[(b*NN + m0 + mm)*KP + kk] = f2bf(v);
    }
  } else {
    // ---- V panel ----
    const int o0 = (r - 160) * 64;
    #pragma unroll
    for (int it = 0; it < 24; ++it){
      int idx = it * 256 + t;
      int rr = idx / KP, kk = idx - rr*KP;
      int o = o0 + rr;
      float v = (kk < 64) ? Wv[o*64 + kk]
              : (kk < 67) ? Wlv[o*3 + (kk - 64)]
              : (kk == 67) ? blv[o] : 0.f;
      Vm[o*KP + kk] = f2bf(v);
    }
  }
}

// ---------------- fused attention ------------------------------------------
// Per WG: (b,h, 64-row n-block), 4 waves; each wave owns an m/d QUARTER.
// Restructured into 4 row-batches (rf): pass1 computes P=exp(e) for 16 rows x
// wave's 256 m-cols and KEEPS P IN 64 VGPRs (pass1 (ms,lane) mapping ==
// pass2 (ds,lane) mapping, so no transpose/LDS needed). Pass2 computes only
// the vc GEMM and multiplies by the register-resident P — the 192 redundant
// e-MFMAs + 256 exp2 per wave of the old pass2 are gone.
__global__ __launch_bounds__(256, 2) void attn_main(
    const float* __restrict__ xs, const short* __restrict__ PTbf,
    const short* __restrict__ Bmat, const short* __restrict__ Vm,
    float* __restrict__ out){
  __shared__ short xsL[64 * 64];        // bf16 [c][n_local]  (8 KB)
  __shared__ short AL[64 * LSTR];       // bf16 A rows [n_local][kk] (13.3 KB)
  __shared__ float redS[16 * 4];        // per-row partial sums x 4 waves (per rf)
  const int t = threadIdx.x, w = t >> 6, lane = t & 63;
  const int q = lane >> 4, ln = lane & 15;
  const int blk = blockIdx.x, nb = blk & 15, bh = blk >> 4;
  const int b = bh >> 3, h = bh & 7;
  const int n0 = nb * 64;

  // ---- stage xs[b][0..63][n0..n0+63] as bf16 ----
  const float* xsb = xs + b * 64 * NN;
  #pragma unroll
  for (int it = 0; it < 4; ++it){
    int idx = it * 256 + t;                     // 1024 float4 units
    int c = idx >> 4, nn4 = (idx & 15) << 2;
    f32x4 v = *(const f32x4*)(xsb + c * NN + n0 + nn4);
    short4v pk;
    #pragma unroll
    for (int j = 0; j < 4; ++j) pk[j] = f2bf(v[j]);
    *(short4v*)(&xsL[c * 64 + nn4]) = pk;
  }
  __syncthreads();

  // ---- build A rows w*16..w*16+15 via MFMA: A = xs^T . PT^T (PT pre-bf16) --
  short8 xf0, xf1;
  #pragma unroll
  for (int j = 0; j < 8; ++j){
    xf0[j] = xsL[(q * 8 + j) * 64 + w * 16 + ln];
    xf1[j] = xsL[(32 + q * 8 + j) * 64 + w * 16 + ln];
  }
  const short* PTh = PTbf + h * 96 * 64;
  #pragma unroll
  for (int kt = 0; kt < 6; ++kt){
    const short* pr = PTh + (kt * 16 + ln) * 64;
    short8 p0 = *(const short8*)(pr + q * 8);
    short8 p1 = *(const short8*)(pr + 32 + q * 8);
    f32x4 a = {0.f, 0.f, 0.f, 0.f};
    a = __builtin_amdgcn_mfma_f32_16x16x32_bf16(xf0, p0, a, 0, 0, 0);
    a = __builtin_amdgcn_mfma_f32_16x16x32_bf16(xf1, p1, a, 0, 0, 0);
    #pragma unroll
    for (int rr = 0; rr < 4; ++rr)
      AL[(w * 16 + q * 4 + rr) * LSTR + kt * 16 + ln] = f2bf(a[rr]);
  }
  __syncthreads();

  const short* Bb = Bmat + b * NN * KP;
  const short* Vh = Vm + h * 1024 * KP;
  float* outp = out + (size_t)bh * (1024 * 1024);
  const float KEXP = 0.045084220f;   // log2(e)/32  (SCALE = sqrt(1024) = 32)

  for (int rf = 0; rf < 4; ++rf){
    // A fragments for this 16-row batch
    const short* ap = &AL[(rf * 16 + ln) * LSTR + q * 8];
    short8 af0 = *(const short8*)(ap);
    short8 af1 = *(const short8*)(ap + 32);
    short8 af2 = *(const short8*)(ap + 64);

    // ---- pass 1: e + exp over wave's m-quarter; keep P in registers ----
    f32x4 P[16];
    f32x4 sum = {0.f, 0.f, 0.f, 0.f};
    short8 bf0, bf1, bf2;
    {
      const short* bp = Bb + (w * 256 + ln) * KP + q * 8;
      bf0 = *(const short8*)(bp);
      bf1 = *(const short8*)(bp + 32);
      bf2 = *(const short8*)(bp + 64);
    }
    #pragma unroll
    for (int ms = 0; ms < 16; ++ms){
      short8 nb0, nb1, nb2;
      {
        int msn = (ms + 1) & 15;
        const short* bp = Bb + (w * 256 + msn * 16 + ln) * KP + q * 8;
        nb0 = *(const short8*)(bp);
        nb1 = *(const short8*)(bp + 32);
        nb2 = *(const short8*)(bp + 64);
      }
      f32x4 e = {0.f, 0.f, 0.f, 0.f};
      e = __builtin_amdgcn_mfma_f32_16x16x32_bf16(af0, bf0, e, 0, 0, 0);
      e = __builtin_amdgcn_mfma_f32_16x16x32_bf16(af1, bf1, e, 0, 0, 0);
      e = __builtin_amdgcn_mfma_f32_16x16x32_bf16(af2, bf2, e, 0, 0, 0);
      f32x4 p;
      #pragma unroll
      for (int rr = 0; rr < 4; ++rr) p[rr] = __builtin_amdgcn_exp2f(e[rr] * KEXP);
      P[ms] = p;
      sum += p;
      bf0 = nb0; bf1 = nb1; bf2 = nb2;
    }
    // reduce over the 16 m-columns (ln bits), then across waves via LDS
    #pragma unroll
    for (int rr = 0; rr < 4; ++rr){
      float s = sum[rr];
      s += __shfl_xor(s, 1); s += __shfl_xor(s, 2);
      s += __shfl_xor(s, 4); s += __shfl_xor(s, 8);
      if (ln == 0) redS[(q * 4 + rr) * 4 + w] = s;
    }
    __syncthreads();
    f32x4 rinv;
    #pragma unroll
    for (int rr = 0; rr < 4; ++rr){
      f32x4 v4 = *(const f32x4*)(&redS[(q * 4 + rr) * 4]);
      rinv[rr] = 1.0f / (v4[0] + v4[1] + v4[2] + v4[3]);
    }

    // ---- pass 2: wave's d-quarter: vc GEMM only, multiply by register P ----
    const short* np = Bb + (n0 + rf * 16 + ln) * KP + q * 8;
    short8 bn0 = *(const short8*)(np);
    short8 bn1 = *(const short8*)(np + 32);
    short8 bn2 = *(const short8*)(np + 64);
    short8 vf0, vf1, vf2;
    {
      const short* vp = Vh + (w * 256 + ln) * KP + q * 8;
      vf0 = *(const short8*)(vp);
      vf1 = *(const short8*)(vp + 32);
      vf2 = *(const short8*)(vp + 64);
    }
    #pragma unroll
    for (int ds = 0; ds < 16; ++ds){
      int d0 = w * 256 + ds * 16;
      short8 nv0, nv1, nv2;
      {
        int dsn = (ds + 1) & 15;
        const short* vp = Vh + (w * 256 + dsn * 16 + ln) * KP + q * 8;
        nv0 = *(const short8*)(vp);
        nv1 = *(const short8*)(vp + 32);
        nv2 = *(const short8*)(vp + 64);
      }
      f32x4 vv = {0.f, 0.f, 0.f, 0.f};
      vv = __builtin_amdgcn_mfma_f32_16x16x32_bf16(bn0, vf0, vv, 0, 0, 0);
      vv = __builtin_amdgcn_mfma_f32_16x16x32_bf16(bn1, vf1, vv, 0, 0, 0);
      vv = __builtin_amdgcn_mfma_f32_16x16x32_bf16(bn2, vf2, vv, 0, 0, 0);
      f32x4 o;
      #pragma unroll
      for (int rr = 0; rr < 4; ++rr)
        o[rr] = P[ds][rr] * rinv[rr] * vv[rr];
      // out[((b*8+h)*1024 + d)*1024 + n]; lane writes row d0+ln, cols n0+rf*16+q*4..+3
      __builtin_nontemporal_store(o, (f32x4*)(outp + (d0 + ln) * NN + n0 + rf * 16 + q * 4));
      vf0 = nv0; vf1 = nv1; vf2 = nv2;
    }
    __syncthreads();   // redS reuse guard for next rf
  }
}

extern "C" void kernel_launch(void* const* d_in, const int* in_sizes, int n_in,
                              void* d_out, int out_size, void* d_ws, size_t ws_size,
                              hipStream_t stream){
  const float* coord = (const float*)d_in[0];
  const float* x     = (const float*)d_in[1];
  const float* nbr   = (const float*)d_in[2];
  const float* Wq    = (const float*)d_in[3];
  const float* Wk    = (const float*)d_in[4];
  const float* Wv    = (const float*)d_in[5];
  const float* Wlq   = (const float*)d_in[6];
  const float* blq   = (const float*)d_in[7];
  const float* Wlv   = (const float*)d_in[8];
  const float* blv   = (const float*)d_in[9];
  float* out = (float*)d_out;

  char* ws = (char*)d_ws;
  short* PTbf = (short*)ws;                       // 8*96*64*2   =   98304 B
  short* Bm   = (short*)(ws + 98304);             // 4*1024*96*2 =  786432 B
  short* Vm   = (short*)(ws + 98304 + 786432);    // 8*1024*96*2 = 1572864 B
  // total ws: 2,457,600 B

  prep_all<<<288, 256, 0, stream>>>(Wq, Wk, Wlq, blq, nbr, coord, Wv, Wlv, blv,
                                    PTbf, Bm, Vm);
  attn_main<<<512, 256, 0, stream>>>(x, PTbf, Bm, Vm, out);
}

// Round 2
// 219.393 us; speedup vs baseline: 1.3530x; 1.3530x over previous
//
#include <hip/hip_runtime.h>

// Dims (fixed by the reference)
#define NN 1024
// K padded: 64 (ns) + 3 (coords) + 1 (bias) = 68 -> pad to 96 = 3 x 32
#define KP 96
#define LSTR 104   // LDS row stride in shorts (208 B; dword stride 52 -> 2-way banks, free)

typedef __attribute__((ext_vector_type(8))) short short8;
typedef __attribute__((ext_vector_type(4))) short short4v;
typedef __attribute__((ext_vector_type(4))) float f32x4;

__device__ __forceinline__ short f2bf(float f){
  unsigned u = __builtin_bit_cast(unsigned, f);
  u += 0x7FFFu + ((u >> 16) & 1u);       // RNE
  return (short)(u >> 16);
}

// ---------------- fused prep: PT panel (bf16) + B panel + V panel ----------
// blocks 0..95   : PTbf[h][kk][c] = bf16( sum_d Wq[h*1024+d][c] * X[d][kk] )
//                  h = r/12, kk octet = (r%12)*8; no atomics (full d-sum per block)
// blocks 96..159 : Bm[b][m][kk] bf16
// blocks 160..287: Vm[o][kk]   bf16
__global__ __launch_bounds__(256) void prep_all(
    const float* __restrict__ Wq, const float* __restrict__ Wk,
    const float* __restrict__ Wlq, const float* __restrict__ blq,
    const float* __restrict__ ns, const float* __restrict__ coord,
    const float* __restrict__ Wv, const float* __restrict__ Wlv,
    const float* __restrict__ blv,
    short* __restrict__ PTbf, short* __restrict__ Bm, short* __restrict__ Vm){
  __shared__ union SU {
    float red[4][64][9];                       // PT partial sums (pad 9: no conflicts)
    struct { float nsT[64][65]; float cst[3][64]; } bb;
  } S;
  const int t = threadIdx.x;
  const int r = blockIdx.x;

  if (r < 96){
    // ---- PT panel ----
    const int h = r / 12, kidx = r % 12, kk0 = kidx * 8;
    const int c = t & 63, p = t >> 6;            // p: 0..3 d-partitions of 256
    if (kidx > 8){                               // pure pad rows: write zeros
      if (p == 0){
        #pragma unroll
        for (int j = 0; j < 8; ++j) PTbf[(h*96 + kk0 + j)*64 + c] = 0;
      }
      return;
    }
    float acc[8];
    #pragma unroll
    for (int j = 0; j < 8; ++j) acc[j] = 0.f;
    if (kidx < 8){
      #pragma unroll 4
      for (int i = 0; i < 256; ++i){
        const int o = h*1024 + p*256 + i;
        const float wq = Wq[o*64 + c];           // coalesced over c
        const float* wk = Wk + o*64 + kk0;       // wave-uniform row
        f32x4 b0 = *(const f32x4*)(wk);
        f32x4 b1 = *(const f32x4*)(wk + 4);
        #pragma unroll
        for (int j = 0; j < 4; ++j){ acc[j] += wq*b0[j]; acc[4+j] += wq*b1[j]; }
      }
    } else {                                     // kidx==8: kk 64..71 (Wlq/blq/pad)
      #pragma unroll 4
      for (int i = 0; i < 256; ++i){
        const int o = h*1024 + p*256 + i;
        const float wq = Wq[o*64 + c];
        acc[0] += wq * Wlq[o*3 + 0];
        acc[1] += wq * Wlq[o*3 + 1];
        acc[2] += wq * Wlq[o*3 + 2];
        acc[3] += wq * blq[o];
      }
    }
    #pragma unroll
    for (int j = 0; j < 8; ++j) S.red[p][c][j] = acc[j];
    __syncthreads();
    if (p == 0){
      #pragma unroll
      for (int j = 0; j < 8; ++j){
        float s = S.red[0][c][j] + S.red[1][c][j] + S.red[2][c][j] + S.red[3][c][j];
        PTbf[(h*96 + kk0 + j)*64 + c] = f2bf(s);
      }
    }
  } else if (r < 160){
    // ---- B panel ----
    const int rb = r - 96;
    const int b = rb >> 4, m0 = (rb & 15) * 64;
    #pragma unroll
    for (int it = 0; it < 16; ++it){
      int idx = it * 256 + t;
      int c = idx >> 6, mm = idx & 63;
      S.bb.nsT[mm][c] = ns[(b*64 + c)*NN + m0 + mm];   // coalesced over mm
    }
    if (t < 192){
      int j = t >> 6, mm = t & 63;
      S.bb.cst[j][mm] = coord[(b*3 + j)*NN + m0 + mm];
    }
    __syncthreads();
    #pragma unroll
    for (int it = 0; it < 24; ++it){
      int idx = it * 256 + t;                          // 64*96 = 6144
      int mm = idx / KP, kk = idx - mm*KP;
      float v = (kk < 64) ? S.bb.nsT[mm][kk]
              : (kk < 67) ? S.bb.cst[kk - 64][mm]
              : (kk == 67) ? 1.f : 0.f;
      Bm[(b*NN + m0 + mm)*KP + kk] = f2bf(v);
    }
  } else {
    // ---- V panel ----
    const int o0 = (r - 160) * 64;
    #pragma unroll
    for (int it = 0; it < 24; ++it){
      int idx = it * 256 + t;
      int rr = idx / KP, kk = idx - rr*KP;
      int o = o0 + rr;
      float v = (kk < 64) ? Wv[o*64 + kk]
              : (kk < 67) ? Wlv[o*3 + (kk - 64)]
              : (kk == 67) ? blv[o] : 0.f;
      Vm[o*KP + kk] = f2bf(v);
    }
  }
}

// ---------------- K4: fused attention (round-0 structure, barrier-free) ----
// Per WG: (b,h, 64-row n-block). Each wave owns an m/d QUARTER (256 of 1024)
// and computes for ALL 64 n-rows (4 row fragments af/bn held in registers).
// Pass1: partial row sums over wave's m-quarter; one LDS reduce across waves.
// Pass2: wave's d-quarter: recompute e + vc GEMM, normalize, f32x4 store.
// (The recompute is ~2.5 us of MFMA chip-wide; caching P instead costs
//  ~500 MB of L2-missing traffic + half-line writes — measured regression.)
__global__ __launch_bounds__(256) void attn_main(
    const float* __restrict__ xs, const short* __restrict__ PTbf,
    const short* __restrict__ Bmat, const short* __restrict__ Vm,
    float* __restrict__ out){
  __shared__ short xsL[64 * 64];        // bf16 [c][n_local]  (8 KB)
  __shared__ short AL[64 * LSTR];       // bf16 A rows [n_local][kk] (13.3 KB)
  __shared__ float redS[64 * 4];        // per-row partial sums x 4 waves
  const int t = threadIdx.x, w = t >> 6, lane = t & 63;
  const int q = lane >> 4, ln = lane & 15;
  const int blk = blockIdx.x, nb = blk & 15, bh = blk >> 4;
  const int b = bh >> 3, h = bh & 7;
  const int n0 = nb * 64;

  // ---- stage xs[b][0..63][n0..n0+63] as bf16 ----
  const float* xsb = xs + b * 64 * NN;
  #pragma unroll
  for (int it = 0; it < 4; ++it){
    int idx = it * 256 + t;                     // 1024 float4 units
    int c = idx >> 4, nn4 = (idx & 15) << 2;
    f32x4 v = *(const f32x4*)(xsb + c * NN + n0 + nn4);
    short4v pk;
    #pragma unroll
    for (int j = 0; j < 4; ++j) pk[j] = f2bf(v[j]);
    *(short4v*)(&xsL[c * 64 + nn4]) = pk;
  }
  __syncthreads();

  // ---- build A rows w*16..w*16+15 via MFMA: A = xs^T . PT^T (PT pre-bf16) --
  short8 xf0, xf1;
  #pragma unroll
  for (int j = 0; j < 8; ++j){
    xf0[j] = xsL[(q * 8 + j) * 64 + w * 16 + ln];
    xf1[j] = xsL[(32 + q * 8 + j) * 64 + w * 16 + ln];
  }
  const short* PTh = PTbf + h * KP * 64;
  #pragma unroll
  for (int kt = 0; kt < 6; ++kt){
    const short* pr = PTh + (kt * 16 + ln) * 64;
    short8 p0 = *(const short8*)(pr + q * 8);
    short8 p1 = *(const short8*)(pr + 32 + q * 8);
    f32x4 a = {0.f, 0.f, 0.f, 0.f};
    a = __builtin_amdgcn_mfma_f32_16x16x32_bf16(xf0, p0, a, 0, 0, 0);
    a = __builtin_amdgcn_mfma_f32_16x16x32_bf16(xf1, p1, a, 0, 0, 0);
    #pragma unroll
    for (int r = 0; r < 4; ++r)
      AL[(w * 16 + q * 4 + r) * LSTR + kt * 16 + ln] = f2bf(a[r]);
  }
  __syncthreads();

  // ---- persistent fragments: all 64 rows ----
  short8 af[4][3], bn[4][3];
  const short* Bb = Bmat + b * NN * KP;
  #pragma unroll
  for (int rf = 0; rf < 4; ++rf){
    #pragma unroll
    for (int s = 0; s < 3; ++s){
      af[rf][s] = *(const short8*)(&AL[(rf * 16 + ln) * LSTR + s * 32 + q * 8]);
      bn[rf][s] = *(const short8*)(Bb + (n0 + rf * 16 + ln) * KP + s * 32 + q * 8);
    }
  }
  const float KEXP = 0.045084220f;   // log2(e)/32  (SCALE = sqrt(1024) = 32)

  // ---- pass 1: partial row sums over wave's m-quarter (no barriers) ----
  float sum[4][4];
  #pragma unroll
  for (int rf = 0; rf < 4; ++rf)
    #pragma unroll
    for (int r = 0; r < 4; ++r) sum[rf][r] = 0.f;

  short8 bf0, bf1, bf2;
  {
    const short* bp = Bb + (w * 256 + ln) * KP + q * 8;
    bf0 = *(const short8*)(bp);
    bf1 = *(const short8*)(bp + 32);
    bf2 = *(const short8*)(bp + 64);
  }
  for (int ms = 0; ms < 16; ++ms){
    short8 nb0, nb1, nb2;
    {
      int msn = (ms + 1) & 15;
      const short* bp = Bb + (w * 256 + msn * 16 + ln) * KP + q * 8;
      nb0 = *(const short8*)(bp);
      nb1 = *(const short8*)(bp + 32);
      nb2 = *(const short8*)(bp + 64);
    }
    #pragma unroll
    for (int rf = 0; rf < 4; ++rf){
      f32x4 e = {0.f, 0.f, 0.f, 0.f};
      e = __builtin_amdgcn_mfma_f32_16x16x32_bf16(af[rf][0], bf0, e, 0, 0, 0);
      e = __builtin_amdgcn_mfma_f32_16x16x32_bf16(af[rf][1], bf1, e, 0, 0, 0);
      e = __builtin_amdgcn_mfma_f32_16x16x32_bf16(af[rf][2], bf2, e, 0, 0, 0);
      #pragma unroll
      for (int r = 0; r < 4; ++r)
        sum[rf][r] += __builtin_amdgcn_exp2f(e[r] * KEXP);
    }
    bf0 = nb0; bf1 = nb1; bf2 = nb2;
  }
  // reduce over the 16 m-columns (ln bits), then across waves via LDS
  #pragma unroll
  for (int rf = 0; rf < 4; ++rf){
    #pragma unroll
    for (int r = 0; r < 4; ++r){
      float s = sum[rf][r];
      s += __shfl_xor(s, 1); s += __shfl_xor(s, 2);
      s += __shfl_xor(s, 4); s += __shfl_xor(s, 8);
      sum[rf][r] = s;
    }
  }
  if (ln == 0){
    #pragma unroll
    for (int rf = 0; rf < 4; ++rf)
      #pragma unroll
      for (int r = 0; r < 4; ++r)
        redS[(rf * 16 + q * 4 + r) * 4 + w] = sum[rf][r];
  }
  __syncthreads();
  float rinv[4][4];
  #pragma unroll
  for (int rf = 0; rf < 4; ++rf){
    #pragma unroll
    for (int r = 0; r < 4; ++r){
      f32x4 v4 = *(const f32x4*)(&redS[(rf * 16 + q * 4 + r) * 4]);
      rinv[rf][r] = 1.0f / (v4[0] + v4[1] + v4[2] + v4[3]);
    }
  }

  // ---- pass 2: wave's d-quarter, recompute e + vc GEMM, store -----------
  float* outp = out + (size_t)bh * (1024 * 1024);
  const short* Vh = Vm + h * 1024 * KP;
  short8 vf0, vf1, vf2;
  {
    const short* bp = Bb + (w * 256 + ln) * KP + q * 8;
    const short* vp = Vh + (w * 256 + ln) * KP + q * 8;
    bf0 = *(const short8*)(bp); bf1 = *(const short8*)(bp + 32); bf2 = *(const short8*)(bp + 64);
    vf0 = *(const short8*)(vp); vf1 = *(const short8*)(vp + 32); vf2 = *(const short8*)(vp + 64);
  }
  for (int ds = 0; ds < 16; ++ds){
    int d0 = w * 256 + ds * 16;
    short8 nb0, nb1, nb2, nv0, nv1, nv2;
    {
      int dsn = (ds + 1) & 15;
      const short* bp = Bb + (w * 256 + dsn * 16 + ln) * KP + q * 8;
      const short* vp = Vh + (w * 256 + dsn * 16 + ln) * KP + q * 8;
      nb0 = *(const short8*)(bp); nb1 = *(const short8*)(bp + 32); nb2 = *(const short8*)(bp + 64);
      nv0 = *(const short8*)(vp); nv1 = *(const short8*)(vp + 32); nv2 = *(const short8*)(vp + 64);
    }
    #pragma unroll
    for (int rf = 0; rf < 4; ++rf){
      f32x4 e  = {0.f, 0.f, 0.f, 0.f};
      f32x4 vv = {0.f, 0.f, 0.f, 0.f};
      e  = __builtin_amdgcn_mfma_f32_16x16x32_bf16(af[rf][0], bf0, e, 0, 0, 0);
      e  = __builtin_amdgcn_mfma_f32_16x16x32_bf16(af[rf][1], bf1, e, 0, 0, 0);
      e  = __builtin_amdgcn_mfma_f32_16x16x32_bf16(af[rf][2], bf2, e, 0, 0, 0);
      vv = __builtin_amdgcn_mfma_f32_16x16x32_bf16(bn[rf][0], vf0, vv, 0, 0, 0);
      vv = __builtin_amdgcn_mfma_f32_16x16x32_bf16(bn[rf][1], vf1, vv, 0, 0, 0);
      vv = __builtin_amdgcn_mfma_f32_16x16x32_bf16(bn[rf][2], vf2, vv, 0, 0, 0);
      f32x4 o;
      #pragma unroll
      for (int r = 0; r < 4; ++r)
        o[r] = __builtin_amdgcn_exp2f(e[r] * KEXP) * rinv[rf][r] * vv[r];
      // out[((b*8+h)*1024 + d)*1024 + n]; lane writes rows d0+ln, cols n0+rf*16+q*4..+3
      *(f32x4*)(outp + (d0 + ln) * NN + n0 + rf * 16 + q * 4) = o;
    }
    bf0 = nb0; bf1 = nb1; bf2 = nb2;
    vf0 = nv0; vf1 = nv1; vf2 = nv2;
  }
}

extern "C" void kernel_launch(void* const* d_in, const int* in_sizes, int n_in,
                              void* d_out, int out_size, void* d_ws, size_t ws_size,
                              hipStream_t stream){
  const float* coord = (const float*)d_in[0];
  const float* x     = (const float*)d_in[1];
  const float* nbr   = (const float*)d_in[2];
  const float* Wq    = (const float*)d_in[3];
  const float* Wk    = (const float*)d_in[4];
  const float* Wv    = (const float*)d_in[5];
  const float* Wlq   = (const float*)d_in[6];
  const float* blq   = (const float*)d_in[7];
  const float* Wlv   = (const float*)d_in[8];
  const float* blv   = (const float*)d_in[9];
  float* out = (float*)d_out;

  char* ws = (char*)d_ws;
  short* PTbf = (short*)ws;                       // 8*96*64*2   =   98304 B
  short* Bm   = (short*)(ws + 98304);             // 4*1024*96*2 =  786432 B
  short* Vm   = (short*)(ws + 98304 + 786432);    // 8*1024*96*2 = 1572864 B
  // total ws: 2,457,600 B

  prep_all<<<288, 256, 0, stream>>>(Wq, Wk, Wlq, blq, nbr, coord, Wv, Wlv, blv,
                                    PTbf, Bm, Vm);
  attn_main<<<512, 256, 0, stream>>>(x, PTbf, Bm, Vm, out);
}